// Round 5
// baseline (186.469 us; speedup 1.0000x reference)
//
#include <hip/hip_runtime.h>

// Problem constants (B=2048, F=512, U=512, G=64, REG_STRENGTH=1.0)
#define B_SZ 2048
#define F_SZ 512
#define U_SZ 512
#define G_SZ 64
#define REG_STRENGTH 1.0f

// prep: histogram/prefix(shfl-scan)/scatter + workspace zeroing.
// gemm: block = (group g, 64-col tile nt). 256 thr = 4 waves x 16 cols.
//   Coalesced global->reg prefetch TWO steps ahead -> bf16 hi/lo split ->
//   XOR-swizzled LDS planes (double-buffered) -> MFMA fragments.
//   In-loop barriers are raw `s_waitcnt lgkmcnt(0); s_barrier` (fused asm):
//   LDS writes sealed, global prefetch loads SURVIVE the barrier (T4 —
//   __syncthreads' vmcnt(0) drain was the r4 stall).
#define THREADS 256
#define NBLOCKS 512   // bid%8 == g%8: a group's 8 blocks share an XCD
#define MC 64         // M rows per chunk (cnt ~ Binom(2048,1/64) ~ 32)
#define BK 64         // K per step
#define NSTEP (F_SZ / BK)  // 8

typedef float f32x4 __attribute__((ext_vector_type(4)));
typedef __bf16 bf16x8 __attribute__((ext_vector_type(8)));

#define MFMA(a, b, c) __builtin_amdgcn_mfma_f32_16x16x32_bf16((a), (b), (c), 0, 0, 0)

// Seal LDS writes for cross-wave visibility WITHOUT draining vmcnt: fused
// asm so no memory op can slip between the wait and the barrier.
#define BARRIER_LGKM() \
  asm volatile("s_waitcnt lgkmcnt(0)\n\ts_barrier" ::: "memory")

// fp32 -> (hi, lo) bf16 split of a float4 (RNE casts). Dropped lo*lo matmul
// term is O(2^-18): fp32-grade accuracy (verified r1-r4, absmax 0.015625).
static __device__ __forceinline__ void split4(const f32x4 v, ushort4* h,
                                              ushort4* l) {
  unsigned short hb[4], lb[4];
#pragma unroll
  for (int i = 0; i < 4; ++i) {
    const __bf16 t = (__bf16)v[i];
    hb[i] = __builtin_bit_cast(unsigned short, t);
    lb[i] = __builtin_bit_cast(unsigned short, (__bf16)(v[i] - (float)t));
  }
  *h = make_ushort4(hb[0], hb[1], hb[2], hb[3]);
  *l = make_ushort4(lb[0], lb[1], lb[2], lb[3]);
}

// Stage one f32x4 into a hi/lo LDS plane pair (row stride 128 B, XOR swizzle).
static __device__ __forceinline__ void stage4(unsigned short* __restrict__ H,
                                              unsigned short* __restrict__ L,
                                              int row, int kq, const f32x4 v) {
  int byte = (row << 7) + (kq << 3);
  byte ^= (row & 7) << 4;
  ushort4 h, l;
  split4(v, &h, &l);
  *(ushort4*)((char*)H + byte) = h;
  *(ushort4*)((char*)L + byte) = l;
}

// ---------------------------------------------------------------------------
// Kernel A: histogram -> wave-parallel exclusive scan -> scatter. Also zeroes
// wsf/done (folds the memset dispatch).
// ---------------------------------------------------------------------------
__global__ __launch_bounds__(1024) void prep_kernel(
    const int* __restrict__ gid, int* __restrict__ counts,
    int* __restrict__ rowstart, int* __restrict__ order,
    float* __restrict__ wsf, unsigned* __restrict__ done) {
  __shared__ int cnt_s[G_SZ];
  __shared__ int cur_s[G_SZ];
  const int tid = threadIdx.x;

  if (tid < G_SZ) cnt_s[tid] = 0;
  if (tid == 0) { wsf[0] = 0.0f; *done = 0u; }
  __syncthreads();

  for (int b = tid; b < B_SZ; b += 1024) atomicAdd(&cnt_s[gid[b]], 1);
  __syncthreads();

  if (tid < G_SZ) {  // wave 0 only: shfl inclusive scan -> exclusive
    const int c = cnt_s[tid];
    int inc = c;
#pragma unroll
    for (int o = 1; o < G_SZ; o <<= 1) {
      const int t = __shfl_up(inc, o, 64);
      if (tid >= o) inc += t;
    }
    counts[tid] = c;
    rowstart[tid] = inc - c;
    cur_s[tid] = inc - c;
  }
  __syncthreads();

  for (int b = tid; b < B_SZ; b += 1024) {
    int pos = atomicAdd(&cur_s[gid[b]], 1);
    order[pos] = b;
  }
}

// ---------------------------------------------------------------------------
// One M-chunk of the grouped GEMM: 2-step-ahead register prefetch, counted
// barriers, double-buffered swizzled LDS, 3x MFMA split-bf16.
// ---------------------------------------------------------------------------
template <bool DOREG>
static __device__ __forceinline__ void run_chunk(
    const float* __restrict__ x, const int* __restrict__ order, int rs,
    int mc, int cnt, const float* __restrict__ wgp,
    const float* __restrict__ w0p, unsigned short* __restrict__ WH0,
    unsigned short* __restrict__ WH1, unsigned short* __restrict__ WL0,
    unsigned short* __restrict__ WL1, unsigned short* __restrict__ XH0,
    unsigned short* __restrict__ XH1, unsigned short* __restrict__ XL0,
    unsigned short* __restrict__ XL1, int srow, int kq, int wv, int llo,
    int lhi, const float* __restrict__ b_mu, int g, int mycol,
    float* __restrict__ out, float& regp) {
  const int rc = min(MC, cnt - mc);
  const int mts = (rc + 15) >> 4;  // active 16-row m-tiles

  const float* xp[4];
#pragma unroll
  for (int u = 0; u < 4; ++u) {
    int sl = mc + srow + (u << 4);
    if (sl >= cnt) sl = cnt - 1;  // dup row; guarded at store
    xp[u] = x + (size_t)order[rs + sl] * F_SZ + (kq << 2);
  }

  f32x4 acc[4];
#pragma unroll
  for (int m = 0; m < 4; ++m) acc[m] = (f32x4){0.f, 0.f, 0.f, 0.f};

  unsigned short* const WH[2] = {WH0, WH1};
  unsigned short* const WL[2] = {WL0, WL1};
  unsigned short* const XH[2] = {XH0, XH1};
  unsigned short* const XL[2] = {XL0, XL1};

  // ---- prologue: issue loads for steps 0 and 1; stage step 0 -> buf 0 ----
  f32x4 wr[2][4], xr[2][4], zr[2][4];
#pragma unroll
  for (int u = 0; u < 4; ++u) wr[0][u] = *(const f32x4*)(wgp + (u << 13));
#pragma unroll
  for (int u = 0; u < 4; ++u) xr[0][u] = *(const f32x4*)(xp[u]);
  if (DOREG) {
#pragma unroll
    for (int u = 0; u < 4; ++u) zr[0][u] = *(const f32x4*)(w0p + (u << 13));
  }
#pragma unroll
  for (int u = 0; u < 4; ++u) wr[1][u] = *(const f32x4*)(wgp + (u << 13) + BK);
#pragma unroll
  for (int u = 0; u < 4; ++u) xr[1][u] = *(const f32x4*)(xp[u] + BK);
  if (DOREG) {
#pragma unroll
    for (int u = 0; u < 4; ++u)
      zr[1][u] = *(const f32x4*)(w0p + (u << 13) + BK);
  }

#pragma unroll
  for (int u = 0; u < 4; ++u) {
    const int row = srow + (u << 4);
    stage4(WH[0], WL[0], row, kq, wr[0][u]);
    stage4(XH[0], XL[0], row, kq, xr[0][u]);
    if (DOREG) {
#pragma unroll
      for (int i = 0; i < 4; ++i) {
        const float d = wr[0][u][i] - zr[0][u][i];
        regp += d * d;
      }
    }
  }
  BARRIER_LGKM();

  // ---- steady state: 8 fully-unrolled steps, static set/buffer indices ----
#pragma unroll
  for (int s = 0; s < NSTEP; ++s) {
    const int cs = s & 1;   // compute buffer / freed register set
    const int ns = cs ^ 1;  // staging buffer / staged register set
    // phase 1: issue loads for step s+2 into the freed set
    if (s + 2 < NSTEP) {
      const int ko = (s + 2) << 6;
#pragma unroll
      for (int u = 0; u < 4; ++u)
        wr[cs][u] = *(const f32x4*)(wgp + (u << 13) + ko);
#pragma unroll
      for (int u = 0; u < 4; ++u) xr[cs][u] = *(const f32x4*)(xp[u] + ko);
      if (DOREG) {
#pragma unroll
        for (int u = 0; u < 4; ++u)
          zr[cs][u] = *(const f32x4*)(w0p + (u << 13) + ko);
      }
    }
    // phase 2: stage step s+1 (set ns) into buf ns; fused W reg-loss
    if (s + 1 < NSTEP) {
#pragma unroll
      for (int u = 0; u < 4; ++u) {
        const int row = srow + (u << 4);
        stage4(WH[ns], WL[ns], row, kq, wr[ns][u]);
        stage4(XH[ns], XL[ns], row, kq, xr[ns][u]);
        if (DOREG) {
#pragma unroll
          for (int i = 0; i < 4; ++i) {
            const float d = wr[ns][u][i] - zr[ns][u][i];
            regp += d * d;
          }
        }
      }
    }
    // phase 3: compute on buf cs (fragments from swizzled LDS)
#pragma unroll
    for (int kk = 0; kk < 2; ++kk) {
      const int wrow = (wv << 4) + llo;
      int wb = (wrow << 7) + (kk << 6) + (lhi << 4);
      wb ^= (wrow & 7) << 4;
      const bf16x8 wh = *(const bf16x8*)((const char*)WH[cs] + wb);
      const bf16x8 wl = *(const bf16x8*)((const char*)WL[cs] + wb);
#pragma unroll
      for (int m = 0; m < 4; ++m) {
        if (m < mts) {
          const int ar = (m << 4) + llo;
          int ab = (ar << 7) + (kk << 6) + (lhi << 4);
          ab ^= (ar & 7) << 4;
          const bf16x8 ah = *(const bf16x8*)((const char*)XH[cs] + ab);
          const bf16x8 al = *(const bf16x8*)((const char*)XL[cs] + ab);
          acc[m] = MFMA(ah, wh, acc[m]);
          acc[m] = MFMA(ah, wl, acc[m]);
          acc[m] = MFMA(al, wh, acc[m]);
        }
      }
    }
    // phase 4: seal LDS writes; vmcnt NOT drained (loads stay in flight)
    BARRIER_LGKM();
  }

  // ---- epilogue: D row = 4*lhi + j, col = llo; scatter by order ----
  const float bias = b_mu[(g << 9) + mycol];
#pragma unroll
  for (int m = 0; m < 4; ++m) {
    if (m < mts) {
#pragma unroll
      for (int j = 0; j < 4; ++j) {
        const int slot = mc + (m << 4) + (lhi << 2) + j;
        if (slot < cnt) {
          out[(size_t)order[rs + slot] * U_SZ + mycol] = acc[m][j] + bias;
        }
      }
    }
  }
}

// ---------------------------------------------------------------------------
// Kernel B: grouped GEMM (LDS-staged MFMA) + fused reg loss + finalize.
// ---------------------------------------------------------------------------
__global__ __launch_bounds__(THREADS, 2) void gemm_kernel(
    const float* __restrict__ x, const float* __restrict__ w_mu,
    const float* __restrict__ b_mu, const float* __restrict__ w0_mu,
    const float* __restrict__ b0_mu, float* __restrict__ out,
    float* __restrict__ wsf, unsigned* __restrict__ done,
    const int* __restrict__ counts, const int* __restrict__ rowstart,
    const int* __restrict__ order) {
  // bf16 planes, row stride 64 elems (128 B), XOR-swizzled. 8 * 8KB = 64 KB.
  __shared__ __align__(16) unsigned short WH[2][MC * BK];
  __shared__ __align__(16) unsigned short WL[2][MC * BK];
  __shared__ __align__(16) unsigned short XH[2][MC * BK];
  __shared__ __align__(16) unsigned short XL[2][MC * BK];
  __shared__ float red_s[4];

  const int bid = blockIdx.x;
  const int g = bid & 63;   // bid%8 == g%8 -> a group's blocks share an XCD
  const int nt = bid >> 6;  // 64-col tile 0..7
  const int n0 = nt << 6;

  const int tid = threadIdx.x;
  const int lane = tid & 63;
  const int wv = tid >> 6;    // wave -> 16-col slice
  const int llo = lane & 15;  // frag row/col within 16-tile
  const int lhi = lane >> 4;  // frag k-subchunk

  const int srow = tid >> 4;  // staging: row base 0..15 (u adds 16,32,48)
  const int kq = tid & 15;    // staging: float4 within row (coalesced)

  const int cnt = counts[g];

  if (cnt > 0) {
    const int rs = rowstart[g];
    const int mycol = n0 + (wv << 4) + llo;
    const float* __restrict__ wgp =
        w_mu + ((size_t)g << 18) + (size_t)(n0 + srow) * F_SZ + (kq << 2);
    const float* __restrict__ w0p =
        w0_mu + (size_t)(n0 + srow) * F_SZ + (kq << 2);

    float regp = 0.0f;
    if (nt == 0) {  // fused bias reg-loss, once per group
#pragma unroll
      for (int u = 0; u < 2; ++u) {
        const int idx = (u << 8) + tid;
        const float d = b_mu[(g << 9) + idx] - b0_mu[idx];
        regp += d * d;
      }
    }

    for (int mc = 0; mc < cnt; mc += MC) {  // one pass in practice (cnt<=64)
      if (mc == 0) {
        run_chunk<true>(x, order, rs, 0, cnt, wgp, w0p, WH[0], WH[1], WL[0],
                        WL[1], XH[0], XH[1], XL[0], XL[1], srow, kq, wv, llo,
                        lhi, b_mu, g, mycol, out, regp);
      } else {
        run_chunk<false>(x, order, rs, mc, cnt, wgp, w0p, WH[0], WH[1], WL[0],
                         WL[1], XH[0], XH[1], XL[0], XL[1], srow, kq, wv, llo,
                         lhi, b_mu, g, mycol, out, regp);
      }
    }

    // ---- block-reduce reg partials, weight by cnt, one atomic ----
#pragma unroll
    for (int o = 32; o > 0; o >>= 1) regp += __shfl_down(regp, o, 64);
    if (lane == 0) red_s[wv] = regp;
    __syncthreads();
    if (tid == 0)
      atomicAdd(wsf, (float)cnt * (red_s[0] + red_s[1] + red_s[2] + red_s[3]));
  }

  // fused finalize: last block writes the reg-loss scalar
  if (tid == 0) {
    __threadfence();
    if (atomicAdd(done, 1u) == (unsigned)(NBLOCKS - 1)) {
      const float v = atomicAdd(wsf, 0.0f);  // coherent device-scope read
      out[(size_t)B_SZ * U_SZ] = REG_STRENGTH * v;
    }
  }
}

extern "C" void kernel_launch(void* const* d_in, const int* in_sizes, int n_in,
                              void* d_out, int out_size, void* d_ws,
                              size_t ws_size, hipStream_t stream) {
  (void)in_sizes; (void)n_in; (void)out_size; (void)ws_size;
  const float* x     = (const float*)d_in[0];
  const int*   gid   = (const int*)d_in[1];
  const float* w_mu  = (const float*)d_in[2];
  const float* b_mu  = (const float*)d_in[3];
  const float* w0_mu = (const float*)d_in[4];
  const float* b0_mu = (const float*)d_in[5];

  float*    wsf      = (float*)d_ws;         // [0]
  unsigned* done     = (unsigned*)d_ws + 1;  // [1]
  int*      counts   = (int*)d_ws + 2;
  int*      rowstart = (int*)d_ws + 2 + G_SZ;
  int*      order    = (int*)d_ws + 2 + 2 * G_SZ;

  prep_kernel<<<1, 1024, 0, stream>>>(gid, counts, rowstart, order, wsf, done);
  gemm_kernel<<<NBLOCKS, THREADS, 0, stream>>>(
      x, w_mu, b_mu, w0_mu, b0_mu, (float*)d_out, wsf, done,
      counts, rowstart, order);
}